// Round 4
// baseline (14552.673 us; speedup 1.0000x reference)
//
#include <hip/hip_runtime.h>
#include <stdint.h>

#define B_   512
#define H_   1024
#define S_   128
#define OUT_ 49

typedef __attribute__((ext_vector_type(8)))  short short8;
typedef __attribute__((ext_vector_type(4)))  float f32x4;
typedef __attribute__((ext_vector_type(16))) float f32x16;

#define VMW(n) asm volatile("s_waitcnt vmcnt(" #n ")" ::: "memory")

__device__ __forceinline__ unsigned short f2bf(float f) {
  union { float f; uint32_t u; } v; v.f = f;
  return (unsigned short)((v.u + 0x7FFFu + ((v.u >> 16) & 1u)) >> 16);  // RNE
}
__device__ __forceinline__ float sigf(float x)   { return 1.0f / (1.0f + __expf(-x)); }
__device__ __forceinline__ float tanhf_(float x) { return 2.0f / (1.0f + __expf(-2.0f * x)) - 1.0f; }

__device__ __forceinline__ void gload16(const void* gp, void* lp) {
  __builtin_amdgcn_global_load_lds(
      (const __attribute__((address_space(1))) void*)gp,
      (__attribute__((address_space(3))) void*)lp, 16, 0, 0);
}

// ---------------------------------------------------------------------------
// n' packing for gate weights: n' = hb16*64 + gp*32 + j*16 + hc
//   gate = gp*2 + j (i,f,g,o), hidden h = hb16*16 + hc.
// Frag-linear dst: [nt(128)][ks(64)][lane(64)][e(8)] bf16,
//   B[n' = nt*32 + (l&31)][k = ks*16 + (l>>5)*8 + e]   (32x32x16 B-operand)
// ---------------------------------------------------------------------------
__global__ void pack_gate_kernel(const float* __restrict__ src, unsigned short* __restrict__ dst) {
  int gid = blockIdx.x * blockDim.x + threadIdx.x;       // 128*64*64 = 524288
  int l  = gid & 63;
  int ks = (gid >> 6) & 63;
  int nt = gid >> 12;
  int np = nt * 32 + (l & 31);
  int hb = np >> 6, r6 = np & 63;
  int gate = (r6 >> 5) * 2 + ((r6 >> 4) & 1);
  int h = hb * 16 + (np & 15);
  int kk = ks * 16 + (l >> 5) * 8;
  const float* p = src + (size_t)(gate * 1024 + h) * 1024 + kk;
  short8 v;
#pragma unroll
  for (int e = 0; e < 8; ++e) v[e] = (short)f2bf(p[e]);
  *reinterpret_cast<short8*>(dst + (size_t)gid * 8) = v;
}

// natural-order frag pack (row = nt*32 + (l&31)); rows >= nrows zero-padded.
__global__ void pack_nat_kernel(const float* __restrict__ src, unsigned short* __restrict__ dst,
                                int NT, int KS, int C, int rowoff, int nrows) {
  int gid = blockIdx.x * blockDim.x + threadIdx.x;
  int total = NT * KS * 64;
  if (gid >= total) return;
  int l  = gid & 63;
  int ks = (gid >> 6) % KS;
  int nt = gid / (KS * 64);
  int row = nt * 32 + (l & 31);
  int kk = ks * 16 + (l >> 5) * 8;
  short8 v;
  if (row < nrows) {
    const float* p = src + (size_t)(rowoff + row) * C + kk;
#pragma unroll
    for (int e = 0; e < 8; ++e) v[e] = (short)f2bf(p[e]);
  } else {
#pragma unroll
    for (int e = 0; e < 8; ++e) v[e] = 0;
  }
  *reinterpret_cast<short8*>(dst + (size_t)gid * 8) = v;
}

__global__ void prep_bias_kernel(const float* __restrict__ bi0, const float* __restrict__ bh0,
                                 const float* __restrict__ bi1, const float* __restrict__ bh1,
                                 float* __restrict__ b0p, float* __restrict__ b1p) {
  int np = blockIdx.x * blockDim.x + threadIdx.x;
  if (np < 4096) {
    int hb = np >> 6, r6 = np & 63;
    int gate = (r6 >> 5) * 2 + ((r6 >> 4) & 1);
    int s = gate * 1024 + hb * 16 + (np & 15);
    b0p[np] = bi0[s] + bh0[s];
    b1p[np] = bi1[s] + bh1[s];
  }
}

// ---------------------------------------------------------------------------
// init: h0/c0 = z @ W^T + b for both layers, K=64 via MFMA.
// h written in A-frag layout (slot 1); c written in C/D-frag layout (2 replicas).
// ---------------------------------------------------------------------------
__global__ __launch_bounds__(256) void init_gemm_kernel(
    const unsigned short* __restrict__ zf, const unsigned short* __restrict__ wip,
    const float* __restrict__ b_hid, const float* __restrict__ b_cell,
    char* __restrict__ h1f, char* __restrict__ h2f,
    char* __restrict__ c0f, char* __restrict__ c1f) {
  __shared__ char tl[8192];
  const int bid = blockIdx.x;                 // 64: layer(2) x nt32(32)
  const int layer = bid >> 5, nt32 = bid & 31;
  const int tid = threadIdx.x, w = tid >> 6, l = tid & 63;
  const unsigned short* wh_ = wip + (size_t)layer * 65536;          // hid frags
  const unsigned short* wc_ = wip + (size_t)(2 + layer) * 65536;    // cell frags
  const float bh = b_hid[layer * 1024 + nt32 * 32 + (l & 31)];
  const float bc = b_cell[layer * 1024 + nt32 * 32 + (l & 31)];
  f32x16 ah[4], ac[4];
#pragma unroll
  for (int m = 0; m < 4; ++m) { ah[m] = (f32x16)0.0f; ac[m] = (f32x16)0.0f; }
#pragma unroll
  for (int ks = 0; ks < 4; ++ks) {
    short8 bhf = *reinterpret_cast<const short8*>((const char*)wh_ + ((size_t)(nt32 * 4 + ks) * 64 + l) * 16);
    short8 bcf = *reinterpret_cast<const short8*>((const char*)wc_ + ((size_t)(nt32 * 4 + ks) * 64 + l) * 16);
#pragma unroll
    for (int m = 0; m < 4; ++m) {
      short8 a = *reinterpret_cast<const short8*>((const char*)zf + ((size_t)((w * 4 + m) * 4 + ks) * 64 + l) * 16);
      ah[m] = __builtin_amdgcn_mfma_f32_32x32x16_bf16(a, bhf, ah[m], 0, 0, 0);
      ac[m] = __builtin_amdgcn_mfma_f32_32x32x16_bf16(a, bcf, ac[m], 0, 0, 0);
    }
  }
  char* hf  = layer ? h2f : h1f;
  char* cfb = layer ? c1f : c0f;
  const int khalf = l >> 5;
#pragma unroll
  for (int m = 0; m < 4; ++m) {
    const int gmt = w * 4 + m;
#pragma unroll
    for (int r = 0; r < 16; ++r) { ah[m][r] += bh; ac[m][r] += bc; }
    // c -> C/D-frag layout, replicated over lane-bit4
    int hb16c = nt32 * 2 + ((l >> 4) & 1);
    int lt = (l & 15) + 32 * khalf;
    float* cb0 = (float*)(cfb + (((size_t)hb16c * 16 + gmt) * 64 + lt) * 64);
    float* cb1 = (float*)(cfb + (((size_t)hb16c * 16 + gmt) * 64 + lt + 16) * 64);
#pragma unroll
    for (int q = 0; q < 4; ++q) {
      f32x4 v = { ac[m][q * 4], ac[m][q * 4 + 1], ac[m][q * 4 + 2], ac[m][q * 4 + 3] };
      *(f32x4*)(cb0 + q * 4) = v;
      *(f32x4*)(cb1 + q * 4) = v;
    }
    // h -> A-frag layout via per-wave LDS transpose tile [32 rr][32 col] bf16
#pragma unroll
    for (int r = 0; r < 16; ++r) {
      int rr = (r & 3) + 8 * (r >> 2) + 4 * khalf;
      *(unsigned short*)(tl + w * 2048 + rr * 64 + (l & 31) * 2) = f2bf(ah[m][r]);
    }
#pragma unroll
    for (int s = 0; s < 2; ++s) {
      short8 hv = *reinterpret_cast<const short8*>(tl + w * 2048 + (l & 31) * 64 + s * 32 + khalf * 16);
      *reinterpret_cast<short8*>(hf + 1048576 + (((size_t)gmt * 64 + nt32 * 2 + s) * 64 + l) * 16) = hv;
    }
  }
}

// ---------------------------------------------------------------------------
// Persistent kernel: 256 WGs (1/CU), 131 supersteps, grid barrier between.
//  bid [0,64):    L0   t=k     (A=h1f, W regs+LDS, cell -> h1f, c0)
//  bid [64,128):  L1h  t=k-2   (A=h2f, + xpart, cell -> h2f, c1)
//  bid [128,256): L1x  t=k-1   (A=h1f, raw f32 -> xp);  u<32 also proj t=k-3
// LDS: [0,64K) per-wave A dbufs (16K each); [64K,128K) shared weights.
// ---------------------------------------------------------------------------
__global__ __launch_bounds__(256, 1) void persist_kernel(
    const unsigned short* __restrict__ w0pk, const unsigned short* __restrict__ w1hpk,
    const unsigned short* __restrict__ w1xpk, const unsigned short* __restrict__ woutpk,
    const float* __restrict__ b0p, const float* __restrict__ b1p, const float* __restrict__ b_out,
    char* __restrict__ h1f, char* __restrict__ h2f, char* __restrict__ xp,
    char* __restrict__ c0f, char* __restrict__ c1f,
    float* __restrict__ out, int* __restrict__ flags) {
  extern __shared__ char smem[];
  const int bid = blockIdx.x, tid = threadIdx.x;
  const int w = tid >> 6, l = tid & 63;
  char* myA  = smem + w * 16384;
  char* WLDS = smem + 65536;

  short8 wreg[64];
  float bias0 = 0.f, bias1 = 0.f, bo = 0.f;
  int hb16 = 0, heavy = 0, isl1h = 0;
  int mq = 0, nt_x = 0, isproj = 0, pmt = 0, pnt = 0;
  char* hbase = nullptr; char* cf = nullptr;

  if (bid < 128) {
    heavy = 1; isl1h = (bid >= 64);
    hb16 = bid & 63;
    const unsigned short* wsrc = isl1h ? w1hpk : w0pk;
    hbase = isl1h ? h2f : h1f;
    cf    = isl1h ? c1f : c0f;
    const float* bp = isl1h ? b1p : b0p;
    bias0 = bp[hb16 * 64 + (l & 31)];
    bias1 = bp[hb16 * 64 + 32 + (l & 31)];
    const int nt0 = hb16 * 2;
#pragma unroll
    for (int ks = 0; ks < 64; ++ks)
      wreg[ks] = *reinterpret_cast<const short8*>((const char*)wsrc + ((size_t)(nt0 * 64 + ks) * 64 + l) * 16);
    // stage gp1 n-tile weights into shared LDS (read-only afterwards)
#pragma unroll
    for (int r = 0; r < 16; ++r)
      gload16((const char*)wsrc + ((size_t)((nt0 + 1) * 64 + r * 4 + w) * 64 + l) * 16,
              WLDS + (r * 4 + w) * 1024);
    VMW(0);
  } else {
    const int u = bid - 128;
    mq = u & 3; nt_x = (u >> 2) * 4 + w;
#pragma unroll
    for (int ks = 0; ks < 64; ++ks)
      wreg[ks] = *reinterpret_cast<const short8*>((const char*)w1xpk + ((size_t)(nt_x * 64 + ks) * 64 + l) * 16);
    if (u < 32) {
      isproj = 1; pmt = u >> 1; pnt = u & 1;
      int o = pnt * 32 + (l & 31);
      bo = (o < OUT_) ? b_out[o] : 0.f;
#pragma unroll
      for (int r = 0; r < 16; ++r)
        gload16((const char*)woutpk + ((size_t)(pnt * 64 + r * 4 + w) * 64 + l) * 16,
                WLDS + (r * 4 + w) * 1024);
      VMW(0);
    }
  }
  __syncthreads();

  for (int k = 0; k < 131; ++k) {
    if (heavy) {
      const int t = isl1h ? (k - 2) : k;
      if (t >= 0 && t < 128) {
        const char* Ab  = hbase + (size_t)((t + 1) & 1) * 1048576;
        char* Ho        = hbase + (size_t)(t & 1) * 1048576;
        const char* xpb = xp + (size_t)(t & 1) * 8388608;
        f32x16 acc0[4], acc1[4];
#pragma unroll
        for (int m = 0; m < 4; ++m) { acc0[m] = (f32x16)0.0f; acc1[m] = (f32x16)0.0f; }
        // prime chunk 0 (wave-private region, no barrier needed anywhere)
#pragma unroll
        for (int q = 0; q < 8; ++q)
          gload16(Ab + ((size_t)((w * 4 + (q >> 1)) * 64 + (q & 1)) * 64 + l) * 16, myA + q * 1024);
#pragma unroll
        for (int kc = 0; kc < 32; ++kc) {
          if (kc < 31) {
#pragma unroll
            for (int q = 0; q < 8; ++q)
              gload16(Ab + ((size_t)((w * 4 + (q >> 1)) * 64 + (kc + 1) * 2 + (q & 1)) * 64 + l) * 16,
                      myA + ((kc + 1) & 1) * 8192 + q * 1024);
            VMW(8);
          } else { VMW(0); }
#pragma unroll
          for (int ksl = 0; ksl < 2; ++ksl) {
            const int ks = kc * 2 + ksl;
            short8 bl = *reinterpret_cast<const short8*>(WLDS + ks * 1024 + l * 16);
#pragma unroll
            for (int m = 0; m < 4; ++m) {
              short8 a = *reinterpret_cast<const short8*>(myA + (kc & 1) * 8192 + (m * 2 + ksl) * 1024 + l * 16);
              acc0[m] = __builtin_amdgcn_mfma_f32_32x32x16_bf16(a, wreg[ks], acc0[m], 0, 0, 0);
              acc1[m] = __builtin_amdgcn_mfma_f32_32x32x16_bf16(a, bl, acc1[m], 0, 0, 0);
            }
          }
        }
        // ---- epilogue: all 4 gates via one shfl_xor(16); cell; h frag-store ----
        const int j16 = (l >> 4) & 1, khalf = l >> 5, hc = l & 15;
#pragma unroll
        for (int m = 0; m < 4; ++m) {
          const int gmt = w * 4 + m;
          f32x16 p0 = acc0[m], p1 = acc1[m];
#pragma unroll
          for (int r = 0; r < 16; ++r) { p0[r] += bias0; p1[r] += bias1; }
          if (isl1h) {
            const float* x0 = (const float*)(xpb + (((size_t)(hb16 * 2) * 16 + gmt) * 64 + l) * 64);
            const float* x1 = (const float*)(xpb + (((size_t)(hb16 * 2 + 1) * 16 + gmt) * 64 + l) * 64);
#pragma unroll
            for (int q = 0; q < 4; ++q) {
              f32x4 v0 = *(const f32x4*)(x0 + q * 4);
              f32x4 v1 = *(const f32x4*)(x1 + q * 4);
#pragma unroll
              for (int e = 0; e < 4; ++e) { p0[q * 4 + e] += v0[e]; p1[q * 4 + e] += v1[e]; }
            }
          }
          float* cb = (float*)(cf + (((size_t)hb16 * 16 + gmt) * 64 + l) * 64);
          f32x4 cq[4];
#pragma unroll
          for (int q = 0; q < 4; ++q) cq[q] = *(const f32x4*)(cb + q * 4);
#pragma unroll
          for (int r = 0; r < 16; ++r) {
            float a0 = p0[r], a1 = p1[r];
            float y0 = __shfl_xor(a0, 16);
            float y1 = __shfl_xor(a1, 16);
            float vi = j16 ? y0 : a0;
            float vf = j16 ? a0 : y0;
            float vg = j16 ? y1 : a1;
            float vo = j16 ? a1 : y1;
            float co = cq[r >> 2][r & 3];
            float cn = sigf(vf) * co + sigf(vi) * tanhf_(vg);
            cq[r >> 2][r & 3] = cn;
            float hv = sigf(vo) * tanhf_(cn);
            const int rr = (r & 3) + 8 * (r >> 2) + 4 * khalf;
            *(unsigned short*)(myA + m * 1024 + rr * 32 + hc * 2) = f2bf(hv);
          }
#pragma unroll
          for (int q = 0; q < 4; ++q) *(f32x4*)(cb + q * 4) = cq[q];
        }
#pragma unroll
        for (int m = 0; m < 4; ++m) {
          short8 hv = *reinterpret_cast<const short8*>(myA + m * 1024 + (l & 31) * 32 + (l >> 5) * 16);
          *reinterpret_cast<short8*>(Ho + (((size_t)(w * 4 + m) * 64 + hb16) * 64 + l) * 16) = hv;
        }
      }
    } else {
      const int tx = k - 1;
      if (tx >= 0 && tx < 128) {
        const char* Ab = h1f + (size_t)(tx & 1) * 1048576;
        char* xpo      = xp + (size_t)(tx & 1) * 8388608;
        f32x16 acc[4];
#pragma unroll
        for (int m = 0; m < 4; ++m) acc[m] = (f32x16)0.0f;
#pragma unroll
        for (int q = 0; q < 8; ++q)
          gload16(Ab + ((size_t)((mq * 4 + (q >> 1)) * 64 + (q & 1)) * 64 + l) * 16, myA + q * 1024);
#pragma unroll
        for (int kc = 0; kc < 32; ++kc) {
          if (kc < 31) {
#pragma unroll
            for (int q = 0; q < 8; ++q)
              gload16(Ab + ((size_t)((mq * 4 + (q >> 1)) * 64 + (kc + 1) * 2 + (q & 1)) * 64 + l) * 16,
                      myA + ((kc + 1) & 1) * 8192 + q * 1024);
            VMW(8);
          } else { VMW(0); }
#pragma unroll
          for (int ksl = 0; ksl < 2; ++ksl) {
            const int ks = kc * 2 + ksl;
#pragma unroll
            for (int m = 0; m < 4; ++m) {
              short8 a = *reinterpret_cast<const short8*>(myA + (kc & 1) * 8192 + (m * 2 + ksl) * 1024 + l * 16);
              acc[m] = __builtin_amdgcn_mfma_f32_32x32x16_bf16(a, wreg[ks], acc[m], 0, 0, 0);
            }
          }
        }
#pragma unroll
        for (int m = 0; m < 4; ++m) {
          float* xo = (float*)(xpo + (((size_t)nt_x * 16 + (mq * 4 + m)) * 64 + l) * 64);
#pragma unroll
          for (int q = 0; q < 4; ++q) {
            f32x4 v = { acc[m][q * 4], acc[m][q * 4 + 1], acc[m][q * 4 + 2], acc[m][q * 4 + 3] };
            *(f32x4*)(xo + q * 4) = v;
          }
        }
      }
      if (isproj) {
        const int tp = k - 3;
        if (tp >= 0 && tp < 128) {
          const char* h2b = h2f + (size_t)(tp & 1) * 1048576;
          f32x16 pa = (f32x16)0.0f;
#pragma unroll 8
          for (int ks = 0; ks < 64; ++ks) {
            short8 b = *reinterpret_cast<const short8*>(WLDS + ks * 1024 + l * 16);
            short8 a = *reinterpret_cast<const short8*>(h2b + ((size_t)(pmt * 64 + ks) * 64 + l) * 16);
            pa = __builtin_amdgcn_mfma_f32_32x32x16_bf16(a, b, pa, 0, 0, 0);
          }
          const int o = pnt * 32 + (l & 31);
          if (o < OUT_) {
#pragma unroll
            for (int r = 0; r < 16; ++r) {
              const int rr = (r & 3) + 8 * (r >> 2) + 4 * (l >> 5);
              const int bb = pmt * 32 + rr;
              out[((size_t)bb * S_ + tp) * OUT_ + o] = sigf(pa[r] + bo);
            }
          }
        }
      }
    }
    // ---- grid barrier k (release writes, arrive, spin, acquire) ----
    __threadfence();
    __syncthreads();
    if (tid == 0) {
      atomicAdd(&flags[k * 4 + (bid & 3)], 1);
      int guard = 0;
      while (true) {
        int s = __hip_atomic_load(&flags[k * 4 + 0], __ATOMIC_RELAXED, __HIP_MEMORY_SCOPE_AGENT)
              + __hip_atomic_load(&flags[k * 4 + 1], __ATOMIC_RELAXED, __HIP_MEMORY_SCOPE_AGENT)
              + __hip_atomic_load(&flags[k * 4 + 2], __ATOMIC_RELAXED, __HIP_MEMORY_SCOPE_AGENT)
              + __hip_atomic_load(&flags[k * 4 + 3], __ATOMIC_RELAXED, __HIP_MEMORY_SCOPE_AGENT);
        if (s >= 256) break;
        __builtin_amdgcn_s_sleep(2);
        if (++guard > (1 << 20)) break;   // bail-out: never hangs the harness
      }
    }
    __syncthreads();
    __threadfence();
  }
}

// ---------------------------------------------------------------------------
extern "C" void kernel_launch(void* const* d_in, const int* in_sizes, int n_in,
                              void* d_out, int out_size, void* d_ws, size_t ws_size,
                              hipStream_t stream) {
  const float* z      = (const float*)d_in[0];
  const float* W_hid  = (const float*)d_in[1];
  const float* b_hid  = (const float*)d_in[2];
  const float* W_cell = (const float*)d_in[3];
  const float* b_cell = (const float*)d_in[4];
  // d_in[5] = W_ih0: multiplied by zeros in the reference -> unused
  const float* W_hh0  = (const float*)d_in[6];
  const float* b_ih0  = (const float*)d_in[7];
  const float* b_hh0  = (const float*)d_in[8];
  const float* W_ih1  = (const float*)d_in[9];
  const float* W_hh1  = (const float*)d_in[10];
  const float* b_ih1  = (const float*)d_in[11];
  const float* b_hh1  = (const float*)d_in[12];
  const float* W_out  = (const float*)d_in[13];
  const float* b_out  = (const float*)d_in[14];
  float* out = (float*)d_out;

  char* ws = (char*)d_ws;
  int*            FLAGS = (int*)(ws + 0);                         // 4 KiB
  float*          B0P   = (float*)(ws + 4096);                    // 16 KiB
  float*          B1P   = (float*)(ws + 20480);                   // 16 KiB
  unsigned short* WOUTp = (unsigned short*)(ws + 65536);          // 128 KiB
  unsigned short* ZFp   = (unsigned short*)(ws + 196608);         // 64 KiB
  unsigned short* WIp   = (unsigned short*)(ws + 262144);         // 512 KiB (hid0,hid1,cell0,cell1)
  unsigned short* W0p   = (unsigned short*)(ws + (1ull << 20));   // 8 MiB
  unsigned short* W1Hp  = (unsigned short*)(ws + (9ull << 20));   // 8 MiB
  unsigned short* W1Xp  = (unsigned short*)(ws + (17ull << 20));  // 8 MiB
  char*           H1F   = ws + (25ull << 20);                     // 2 MiB (2 slots)
  char*           H2F   = ws + (27ull << 20);                     // 2 MiB
  char*           XP    = ws + (29ull << 20);                     // 16 MiB (2 slots)
  char*           C0F   = ws + (45ull << 20);                     // 4 MiB
  char*           C1F   = ws + (49ull << 20);                     // 4 MiB

  hipMemsetAsync(FLAGS, 0, 4096, stream);
  pack_gate_kernel<<<2048, 256, 0, stream>>>(W_hh0, W0p);
  pack_gate_kernel<<<2048, 256, 0, stream>>>(W_hh1, W1Hp);
  pack_gate_kernel<<<2048, 256, 0, stream>>>(W_ih1, W1Xp);
  pack_nat_kernel<<<32, 256, 0, stream>>>(W_out, WOUTp, 2, 64, 1024, 0, 49);
  pack_nat_kernel<<<16, 256, 0, stream>>>(z, ZFp, 16, 4, 64, 0, 512);
  pack_nat_kernel<<<32, 256, 0, stream>>>(W_hid,  WIp,          32, 4, 64, 0,    1024);
  pack_nat_kernel<<<32, 256, 0, stream>>>(W_hid,  WIp + 65536,  32, 4, 64, 1024, 1024);
  pack_nat_kernel<<<32, 256, 0, stream>>>(W_cell, WIp + 131072, 32, 4, 64, 0,    1024);
  pack_nat_kernel<<<32, 256, 0, stream>>>(W_cell, WIp + 196608, 32, 4, 64, 1024, 1024);
  prep_bias_kernel<<<16, 256, 0, stream>>>(b_ih0, b_hh0, b_ih1, b_hh1, B0P, B1P);
  init_gemm_kernel<<<64, 256, 0, stream>>>(ZFp, WIp, b_hid, b_cell, H1F, H2F, C0F, C1F);

  static bool attr_set = false;
  if (!attr_set) {
    hipFuncSetAttribute((const void*)persist_kernel,
                        hipFuncAttributeMaxDynamicSharedMemorySize, 131072);
    attr_set = true;
  }
  persist_kernel<<<256, 256, 131072, stream>>>(
      W0p, W1Hp, W1Xp, WOUTp, B0P, B1P, b_out,
      H1F, H2F, XP, C0F, C1F, out, FLAGS);
}